// Round 1
// baseline (3417.030 us; speedup 1.0000x reference)
//
#include <hip/hip_runtime.h>
#include <hip/hip_bf16.h>
#include <cstdint>
#include <cstddef>

#define BN_EPS 1e-5f

// ------------------------------------------------------------------
// PFN: x = pillars(640000,9) @ lin_w.T + lin_b ; BN over rows; relu; max over N=32
// ------------------------------------------------------------------

// grid 625 x 256 threads. Each block handles 1024 rows in 32 chunks of 32 rows.
// thread: c = tid&63 (channel), rs = tid>>6 (row slice 0..3)
__global__ __launch_bounds__(256) void pfn_stats(
    const float* __restrict__ pillars, const float* __restrict__ lin_w,
    const float* __restrict__ lin_b, float* __restrict__ acc) {
  __shared__ float s_p[288];
  __shared__ float red[512];
  int tid = threadIdx.x;
  int c = tid & 63, rs = tid >> 6;
  float w[9];
#pragma unroll
  for (int d = 0; d < 9; ++d) w[d] = lin_w[c * 9 + d];
  float bl = lin_b[c];
  float s = 0.f, s2 = 0.f;
  long base_row = (long)blockIdx.x * 1024;
  for (int ch = 0; ch < 32; ++ch) {
    long crow = base_row + ch * 32;
    __syncthreads();
    for (int i = tid; i < 288; i += 256) s_p[i] = pillars[crow * 9 + i];
    __syncthreads();
#pragma unroll
    for (int k = 0; k < 8; ++k) {
      int rl = rs * 8 + k;
      const float* pr = &s_p[rl * 9];
      float y = bl;
#pragma unroll
      for (int d = 0; d < 9; ++d) y += pr[d] * w[d];
      s += y;
      s2 += y * y;
    }
  }
  red[tid] = s;
  red[tid + 256] = s2;
  __syncthreads();
  if (rs == 0) {
    float ts = red[c] + red[c + 64] + red[c + 128] + red[c + 192];
    float t2 = red[256 + c] + red[256 + c + 64] + red[256 + c + 128] + red[256 + c + 192];
    atomicAdd(&acc[c], ts);
    atomicAdd(&acc[c + 64], t2);
  }
}

__global__ void pfn_finalize(const float* __restrict__ acc, const float* __restrict__ g,
                             const float* __restrict__ b, float* __restrict__ ss) {
  int c = threadIdx.x;  // 64 threads
  const float invN = 1.f / 640000.f;
  float m = acc[c] * invN;
  float v = acc[c + 64] * invN - m * m;
  v = fmaxf(v, 0.f);
  float inv = rsqrtf(v + BN_EPS);
  float sc = g[c] * inv;
  ss[c] = sc;
  ss[c + 64] = b[c] - m * sc;
}

// grid 5000 x 256. Block handles 4 pillars; thread: c = tid&63, pe = tid>>6
__global__ __launch_bounds__(256) void pfn_feats(
    const float* __restrict__ pillars, const float* __restrict__ lin_w,
    const float* __restrict__ lin_b, const float* __restrict__ ss,
    float* __restrict__ feats) {
  __shared__ float s_p[1152];
  int tid = threadIdx.x;
  int c = tid & 63, pe = tid >> 6;
  long pb = (long)blockIdx.x * 4;
  for (int i = tid; i < 1152; i += 256) s_p[i] = pillars[pb * 288 + i];
  float w[9];
#pragma unroll
  for (int d = 0; d < 9; ++d) w[d] = lin_w[c * 9 + d];
  float bl = lin_b[c];
  float sc = ss[c], sh = ss[c + 64];
  __syncthreads();
  const float* pp = &s_p[pe * 288];
  float m = -1e30f;
#pragma unroll 4
  for (int n = 0; n < 32; ++n) {
    float y = bl;
#pragma unroll
    for (int d = 0; d < 9; ++d) y += pp[n * 9 + d] * w[d];
    float v = fmaxf(y * sc + sh, 0.f);
    m = fmaxf(m, v);
  }
  feats[(pb + pe) * 64 + c] = m;
}

// ------------------------------------------------------------------
// Scatter (numpy last-write-wins: highest pillar index wins a duplicate cell)
// ------------------------------------------------------------------

__global__ void scatter_winner(const int* __restrict__ coords, int* __restrict__ winner,
                               int P) {
  int p = blockIdx.x * 256 + threadIdx.x;
  if (p >= P) return;
  int y = coords[p * 3 + 1], x = coords[p * 3 + 2];
  if (y >= 0 && y < 666 && x >= 0 && x < 666) atomicMax(&winner[y * 666 + x], p);
}

__global__ void scatter_img(const int* __restrict__ coords, const int* __restrict__ winner,
                            const float* __restrict__ feats, float* __restrict__ img,
                            int P) {
  int idx = blockIdx.x * 256 + threadIdx.x;
  int p = idx >> 6, c = idx & 63;
  if (p >= P) return;
  int y = coords[p * 3 + 1], x = coords[p * 3 + 2];
  if (y >= 0 && y < 666 && x >= 0 && x < 666) {
    int cell = y * 666 + x;
    if (winner[cell] == p) img[(size_t)c * (666 * 666) + cell] = feats[p * 64 + c];
  }
}

// ------------------------------------------------------------------
// Direct 3x3 SAME conv, NCHW, fp32. Block 256 = (tx 0..31, ty 0..7),
// tile 32x32 output pixels, 4 consecutive y-pixels per thread, OCB oc per block.
// ------------------------------------------------------------------

template <int CIN, int OCB>
__global__ __launch_bounds__(256) void conv3x3(
    const float* __restrict__ in, const float* __restrict__ w,
    const float* __restrict__ bias, float* __restrict__ out, int H, int W) {
  __shared__ float s_in[34 * 34];
  __shared__ float s_w[OCB * 9];
  int tid = threadIdx.x;
  int tx = tid & 31, ty = tid >> 5;
  int x0 = blockIdx.x * 32, y0 = blockIdx.y * 32;
  int ocb = blockIdx.z * OCB;
  float acc[OCB][4];
#pragma unroll
  for (int o = 0; o < OCB; ++o)
#pragma unroll
    for (int j = 0; j < 4; ++j) acc[o][j] = 0.f;

  for (int ic = 0; ic < CIN; ++ic) {
    __syncthreads();  // protect s_in/s_w from previous iteration's readers
    const float* inc = in + (size_t)ic * H * W;
    for (int i = tid; i < 34 * 34; i += 256) {
      int r = i / 34, cc = i - r * 34;
      int gy = y0 - 1 + r, gx = x0 - 1 + cc;
      float v = 0.f;
      if (gy >= 0 && gy < H && gx >= 0 && gx < W) v = inc[(size_t)gy * W + gx];
      s_in[i] = v;
    }
    if (tid < OCB * 9) {
      int o = tid / 9, k = tid - o * 9;
      s_w[tid] = w[((size_t)(ocb + o) * CIN + ic) * 9 + k];
    }
    __syncthreads();
    float r6[6][3];
    int py0 = ty * 4;
#pragma unroll
    for (int j = 0; j < 6; ++j)
#pragma unroll
      for (int k = 0; k < 3; ++k) r6[j][k] = s_in[(py0 + j) * 34 + tx + k];
#pragma unroll
    for (int o = 0; o < OCB; ++o) {
#pragma unroll
      for (int j = 0; j < 4; ++j) {
        float a = acc[o][j];
#pragma unroll
        for (int ky = 0; ky < 3; ++ky)
#pragma unroll
          for (int kx = 0; kx < 3; ++kx) a += r6[j + ky][kx] * s_w[o * 9 + ky * 3 + kx];
        acc[o][j] = a;
      }
    }
  }
  int px = x0 + tx;
#pragma unroll
  for (int o = 0; o < OCB; ++o) {
    float bv = bias[ocb + o];
#pragma unroll
    for (int j = 0; j < 4; ++j) {
      int py = y0 + ty * 4 + j;
      if (py < H && px < W)
        out[((size_t)(ocb + o) * H + py) * W + px] = acc[o][j] + bv;
    }
  }
}

// ------------------------------------------------------------------
// Per-channel sum / sumsq over spatial. grid (nchunk, C). acc: sum[c], sumsq[c+256]
// ------------------------------------------------------------------

__global__ __launch_bounds__(256) void channel_stats(const float* __restrict__ x,
                                                     float* __restrict__ acc, int HW) {
  int c = blockIdx.y;
  const float* p = x + (size_t)c * HW;
  int stride = gridDim.x * 256;
  float s = 0.f, s2 = 0.f;
  for (int i = blockIdx.x * 256 + threadIdx.x; i < HW; i += stride) {
    float v = p[i];
    s += v;
    s2 += v * v;
  }
  __shared__ float rs_[256], rs2_[256];
  int tid = threadIdx.x;
  rs_[tid] = s;
  rs2_[tid] = s2;
  __syncthreads();
  for (int o = 128; o > 0; o >>= 1) {
    if (tid < o) {
      rs_[tid] += rs_[tid + o];
      rs2_[tid] += rs2_[tid + o];
    }
    __syncthreads();
  }
  if (tid == 0) {
    atomicAdd(&acc[c], rs_[0]);
    atomicAdd(&acc[c + 256], rs2_[0]);
  }
}

__global__ void bn_finalize(const float* __restrict__ acc, const float* __restrict__ g,
                            const float* __restrict__ b, float* __restrict__ ss, int C,
                            float invN) {
  int c = threadIdx.x;
  if (c >= C) return;
  float m = acc[c] * invN;
  float v = acc[c + 256] * invN - m * m;
  v = fmaxf(v, 0.f);
  float inv = rsqrtf(v + BN_EPS);
  float sc = g[c] * inv;
  ss[c] = sc;
  ss[c + 256] = b[c] - m * sc;
}

// BN + relu + 2x2 max pool (VALID). out (C,OH,OW) from in (C,H,W)
__global__ __launch_bounds__(256) void bn_relu_pool(const float* __restrict__ in,
                                                    const float* __restrict__ ss,
                                                    float* __restrict__ out, int H, int W,
                                                    int OH, int OW, int C) {
  int idx = blockIdx.x * 256 + threadIdx.x;
  int total = C * OH * OW;
  if (idx >= total) return;
  int ox = idx % OW;
  int t = idx / OW;
  int oy = t % OH;
  int c = t / OH;
  float sc = ss[c], sh = ss[c + 256];
  const float* p = in + (size_t)c * H * W + (size_t)(2 * oy) * W + 2 * ox;
  float a = fmaxf(p[0] * sc + sh, 0.f);
  float b_ = fmaxf(p[1] * sc + sh, 0.f);
  float cc = fmaxf(p[W] * sc + sh, 0.f);
  float d = fmaxf(p[W + 1] * sc + sh, 0.f);
  out[idx] = fmaxf(fmaxf(a, b_), fmaxf(cc, d));
}

// BN + relu in place
__global__ __launch_bounds__(256) void bn_relu(float* __restrict__ x,
                                               const float* __restrict__ ss, int HW,
                                               int total) {
  int idx = blockIdx.x * 256 + threadIdx.x;
  if (idx >= total) return;
  int c = idx / HW;
  x[idx] = fmaxf(x[idx] * ss[c] + ss[c + 256], 0.f);
}

// ------------------------------------------------------------------

extern "C" void kernel_launch(void* const* d_in, const int* in_sizes, int n_in,
                              void* d_out, int out_size, void* d_ws, size_t ws_size,
                              hipStream_t stream) {
  (void)in_sizes; (void)n_in; (void)out_size; (void)ws_size;
  const float* pillars = (const float*)d_in[0];
  const int* coords = (const int*)d_in[1];
  const float* lin_w = (const float*)d_in[2];
  const float* lin_b = (const float*)d_in[3];
  const float* pfn_g = (const float*)d_in[4];
  const float* pfn_b = (const float*)d_in[5];
  const float* c1_w = (const float*)d_in[6];
  const float* c1_b = (const float*)d_in[7];
  const float* bn1_g = (const float*)d_in[8];
  const float* bn1_b = (const float*)d_in[9];
  const float* c2_w = (const float*)d_in[10];
  const float* c2_b = (const float*)d_in[11];
  const float* bn2_g = (const float*)d_in[12];
  const float* bn2_b = (const float*)d_in[13];
  const float* h1_w = (const float*)d_in[14];
  const float* h1_b = (const float*)d_in[15];
  const float* hbn_g = (const float*)d_in[16];
  const float* hbn_b = (const float*)d_in[17];
  const float* hb_w = (const float*)d_in[18];
  const float* hb_b = (const float*)d_in[19];
  const float* hc_w = (const float*)d_in[20];
  const float* hc_b = (const float*)d_in[21];
  float* out = (float*)d_out;

  // workspace layout
  char* ws = (char*)d_ws;
  float* pfn_acc = (float*)ws;        // 128 floats (sum[64], sumsq[64])
  float* pfn_ss = pfn_acc + 128;      // 128 floats (scale[64], shift[64])
  float* bn_acc = pfn_acc + 256;      // 512 floats (sum[256], sumsq[256])
  float* bn_ss = pfn_acc + 768;       // 512 floats (scale[256], shift[256])
  int* winner = (int*)(ws + 8192);                         // 443556 ints
  float* feats = (float*)(ws + 8192 + 1774592);            // 20000*64 floats
  float* bufA = (float*)(ws + 8192 + 1774592 + 5120000);   // 28,387,584 floats
  float* bufB = bufA + (size_t)64 * 666 * 666;             // same size

  const int HW1 = 666 * 666;   // 443556
  const int HW2 = 333 * 333;   // 110889
  const int HW3 = 166 * 166;   // 27556

  // ---- PFN ----
  hipMemsetAsync(pfn_acc, 0, 128 * sizeof(float), stream);
  pfn_stats<<<625, 256, 0, stream>>>(pillars, lin_w, lin_b, pfn_acc);
  pfn_finalize<<<1, 64, 0, stream>>>(pfn_acc, pfn_g, pfn_b, pfn_ss);
  pfn_feats<<<5000, 256, 0, stream>>>(pillars, lin_w, lin_b, pfn_ss, feats);

  // ---- scatter ----
  hipMemsetAsync(winner, 0xFF, HW1 * sizeof(int), stream);
  scatter_winner<<<(20000 + 255) / 256, 256, 0, stream>>>(coords, winner, 20000);
  hipMemsetAsync(bufA, 0, (size_t)64 * HW1 * sizeof(float), stream);
  scatter_img<<<5000, 256, 0, stream>>>(coords, winner, feats, bufA, 20000);

  // ---- conv1 (64->64, 666x666) ----
  conv3x3<64, 8><<<dim3(21, 21, 8), 256, 0, stream>>>(bufA, c1_w, c1_b, bufB, 666, 666);
  hipMemsetAsync(bn_acc, 0, 512 * sizeof(float), stream);
  channel_stats<<<dim3(32, 64), 256, 0, stream>>>(bufB, bn_acc, HW1);
  bn_finalize<<<1, 256, 0, stream>>>(bn_acc, bn1_g, bn1_b, bn_ss, 64, 1.f / (float)HW1);
  {
    int total = 64 * HW2;
    bn_relu_pool<<<(total + 255) / 256, 256, 0, stream>>>(bufB, bn_ss, bufA, 666, 666,
                                                          333, 333, 64);
  }

  // ---- conv2 (64->128, 333x333) ----
  conv3x3<64, 8><<<dim3(11, 11, 16), 256, 0, stream>>>(bufA, c2_w, c2_b, bufB, 333, 333);
  hipMemsetAsync(bn_acc, 0, 512 * sizeof(float), stream);
  channel_stats<<<dim3(32, 128), 256, 0, stream>>>(bufB, bn_acc, HW2);
  bn_finalize<<<1, 256, 0, stream>>>(bn_acc, bn2_g, bn2_b, bn_ss, 128, 1.f / (float)HW2);
  {
    int total = 128 * HW3;
    bn_relu_pool<<<(total + 255) / 256, 256, 0, stream>>>(bufB, bn_ss, bufA, 333, 333,
                                                          166, 166, 128);
  }

  // ---- h1 (128->256, 166x166) ----
  conv3x3<128, 8><<<dim3(6, 6, 32), 256, 0, stream>>>(bufA, h1_w, h1_b, bufB, 166, 166);
  hipMemsetAsync(bn_acc, 0, 512 * sizeof(float), stream);
  channel_stats<<<dim3(32, 256), 256, 0, stream>>>(bufB, bn_acc, HW3);
  bn_finalize<<<1, 256, 0, stream>>>(bn_acc, hbn_g, hbn_b, bn_ss, 256, 1.f / (float)HW3);
  {
    int total = 256 * HW3;
    bn_relu<<<(total + 255) / 256, 256, 0, stream>>>(bufB, bn_ss, HW3, total);
  }

  // ---- heads ----
  conv3x3<256, 7><<<dim3(6, 6, 3), 256, 0, stream>>>(bufB, hb_w, hb_b, out, 166, 166);
  conv3x3<256, 3><<<dim3(6, 6, 1), 256, 0, stream>>>(bufB, hc_w, hc_b,
                                                     out + (size_t)21 * HW3, 166, 166);
}

// Round 2
// 573.494 us; speedup vs baseline: 5.9583x; 5.9583x over previous
//
#include <hip/hip_runtime.h>
#include <hip/hip_bf16.h>
#include <cstdint>
#include <cstddef>

#define BN_EPS 1e-5f

typedef short short8 __attribute__((ext_vector_type(8)));
typedef float float16 __attribute__((ext_vector_type(16)));
typedef unsigned short ushort_t;

__device__ __forceinline__ float bf2f(ushort_t u) {
  return __uint_as_float(((unsigned int)u) << 16);
}
__device__ __forceinline__ ushort_t f2bf(float f) {
  unsigned int u = __float_as_uint(f);
  u += 0x7FFFu + ((u >> 16) & 1u);
  return (ushort_t)(u >> 16);
}

// ------------------------------------------------------------------
// PFN (fp32, unchanged from round 1 — passed)
// ------------------------------------------------------------------

__global__ __launch_bounds__(256) void pfn_stats(
    const float* __restrict__ pillars, const float* __restrict__ lin_w,
    const float* __restrict__ lin_b, float* __restrict__ acc) {
  __shared__ float s_p[288];
  __shared__ float red[512];
  int tid = threadIdx.x;
  int c = tid & 63, rs = tid >> 6;
  float w[9];
#pragma unroll
  for (int d = 0; d < 9; ++d) w[d] = lin_w[c * 9 + d];
  float bl = lin_b[c];
  float s = 0.f, s2 = 0.f;
  long base_row = (long)blockIdx.x * 1024;
  for (int ch = 0; ch < 32; ++ch) {
    long crow = base_row + ch * 32;
    __syncthreads();
    for (int i = tid; i < 288; i += 256) s_p[i] = pillars[crow * 9 + i];
    __syncthreads();
#pragma unroll
    for (int k = 0; k < 8; ++k) {
      const float* pr = &s_p[(rs * 8 + k) * 9];
      float y = bl;
#pragma unroll
      for (int d = 0; d < 9; ++d) y += pr[d] * w[d];
      s += y;
      s2 += y * y;
    }
  }
  red[tid] = s;
  red[tid + 256] = s2;
  __syncthreads();
  if (rs == 0) {
    float ts = red[c] + red[c + 64] + red[c + 128] + red[c + 192];
    float t2 = red[256 + c] + red[256 + c + 64] + red[256 + c + 128] + red[256 + c + 192];
    atomicAdd(&acc[c], ts);
    atomicAdd(&acc[c + 64], t2);
  }
}

__global__ void pfn_finalize(const float* __restrict__ acc, const float* __restrict__ g,
                             const float* __restrict__ b, float* __restrict__ ss) {
  int c = threadIdx.x;  // 64 threads
  const float invN = 1.f / 640000.f;
  float m = acc[c] * invN;
  float v = acc[c + 64] * invN - m * m;
  v = fmaxf(v, 0.f);
  float inv = rsqrtf(v + BN_EPS);
  float sc = g[c] * inv;
  ss[c] = sc;
  ss[c + 64] = b[c] - m * sc;
}

__global__ __launch_bounds__(256) void pfn_feats(
    const float* __restrict__ pillars, const float* __restrict__ lin_w,
    const float* __restrict__ lin_b, const float* __restrict__ ss,
    float* __restrict__ feats) {
  __shared__ float s_p[1152];
  int tid = threadIdx.x;
  int c = tid & 63, pe = tid >> 6;
  long pb = (long)blockIdx.x * 4;
  for (int i = tid; i < 1152; i += 256) s_p[i] = pillars[pb * 288 + i];
  float w[9];
#pragma unroll
  for (int d = 0; d < 9; ++d) w[d] = lin_w[c * 9 + d];
  float bl = lin_b[c];
  float sc = ss[c], sh = ss[c + 64];
  __syncthreads();
  const float* pp = &s_p[pe * 288];
  float m = -1e30f;
#pragma unroll 4
  for (int n = 0; n < 32; ++n) {
    float y = bl;
#pragma unroll
    for (int d = 0; d < 9; ++d) y += pp[n * 9 + d] * w[d];
    float v = fmaxf(y * sc + sh, 0.f);
    m = fmaxf(m, v);
  }
  feats[(pb + pe) * 64 + c] = m;
}

// ------------------------------------------------------------------
// Scatter into padded bf16 HWC canvas (numpy last-write-wins)
// ------------------------------------------------------------------

__global__ void scatter_winner(const int* __restrict__ coords, int* __restrict__ winner,
                               int P) {
  int p = blockIdx.x * 256 + threadIdx.x;
  if (p >= P) return;
  int y = coords[p * 3 + 1], x = coords[p * 3 + 2];
  if (y >= 0 && y < 666 && x >= 0 && x < 666) atomicMax(&winner[y * 666 + x], p);
}

__global__ void scatter_img(const int* __restrict__ coords, const int* __restrict__ winner,
                            const float* __restrict__ feats, ushort_t* __restrict__ img,
                            int P, int PW) {
  int idx = blockIdx.x * 256 + threadIdx.x;
  int p = idx >> 6, c = idx & 63;
  if (p >= P) return;
  int y = coords[p * 3 + 1], x = coords[p * 3 + 2];
  if (y >= 0 && y < 666 && x >= 0 && x < 666) {
    if (winner[y * 666 + x] == p)
      img[((size_t)(y + 1) * PW + (x + 1)) * 64 + c] = f2bf(feats[p * 64 + c]);
  }
}

// ------------------------------------------------------------------
// Weight prep: OIHW fp32 -> fragment-ordered bf16
// layout: [cc][pos][s][ntg][lane 64][8]  (lane l: n=ntg*32+(l&31), k=s*16+(l>>5)*8+j)
// ------------------------------------------------------------------

__global__ void prep_w(const float* __restrict__ w, ushort_t* __restrict__ w2, int C,
                       int N, int Ntg, int chunks) {
  int u = blockIdx.x * 256 + threadIdx.x;
  int total = chunks * 9 * 2 * Ntg * 64;
  if (u >= total) return;
  int l = u & 63;
  int g = u >> 6;
  int ntg = g % Ntg;
  int g2 = g / Ntg;
  int s = g2 & 1;
  int g3 = g2 >> 1;
  int pos = g3 % 9;
  int cc = g3 / 9;
  int n = ntg * 32 + (l & 31);
  int c0 = cc * 32 + s * 16 + (l >> 5) * 8;
  ushort_t o8[8];
#pragma unroll
  for (int j = 0; j < 8; ++j) {
    int c = c0 + j;
    float v = (n < N && c < C) ? w[((size_t)n * C + c) * 9 + pos] : 0.f;
    o8[j] = f2bf(v);
  }
  *(uint4*)&w2[(size_t)u * 8] = *(const uint4*)o8;
}

// merged heads: n<21 -> hb_w, 21..23 -> hc_w, >=24 -> 0.  C=256, Ntg=1, chunks=8
__global__ void prep_w_head(const float* __restrict__ hb, const float* __restrict__ hc,
                            ushort_t* __restrict__ w2) {
  int u = blockIdx.x * 256 + threadIdx.x;
  int total = 8 * 9 * 2 * 64;
  if (u >= total) return;
  int l = u & 63;
  int g = u >> 6;
  int s = g & 1;
  int g3 = g >> 1;
  int pos = g3 % 9;
  int cc = g3 / 9;
  int n = l & 31;
  int c0 = cc * 32 + s * 16 + (l >> 5) * 8;
  ushort_t o8[8];
#pragma unroll
  for (int j = 0; j < 8; ++j) {
    int c = c0 + j;
    float v = 0.f;
    if (n < 21) v = hb[((size_t)n * 256 + c) * 9 + pos];
    else if (n < 24) v = hc[((size_t)(n - 21) * 256 + c) * 9 + pos];
    o8[j] = f2bf(v);
  }
  *(uint4*)&w2[(size_t)u * 8] = *(const uint4*)o8;
}

// ------------------------------------------------------------------
// Implicit-GEMM 3x3 conv via v_mfma_f32_32x32x16_bf16.
// Block = 4 waves. Output tile 64 px wide x 4 rows, N-per-block = NTILES*32 oc.
// Wave w handles output row y0+w, 2 M-tiles of 32 px, NTILES n-tiles.
// Input: padded bf16 HWC, logical (y,x) at ((y+1)*PW + (x+1))*C.
// K chunked by 32 ch; per chunk stage input 6x66x32 (xor-swizzled) + weights.
// ------------------------------------------------------------------

template <int NTILES, bool HEAD>
__global__ __launch_bounds__(256, 2) void conv_mfma(
    const ushort_t* __restrict__ in, const ushort_t* __restrict__ w2,
    const float* __restrict__ bias, const float* __restrict__ bias2,
    ushort_t* __restrict__ obf, float* __restrict__ oba, float* __restrict__ obb,
    int PW, int W, int H, int C, int Ntg) {
  __shared__ ushort_t s_in[6 * 66 * 32];            // 25344 B
  __shared__ ushort_t s_w[9 * 2 * NTILES * 512];    // 36864 B (NTILES=2)
  const int tid = threadIdx.x;
  const int lane = tid & 63, wv = tid >> 6;
  const int lc = lane & 31, lh = lane >> 5;
  const int x0 = blockIdx.x * 64, y0 = blockIdx.y * 4;
  const int z = blockIdx.z;
  const int chunks = C >> 5;
  const int Ntot = Ntg * 32;

  // per-lane A-address precompute (short offsets within an s_in row)
  int pc[2][2][3];
#pragma unroll
  for (int s = 0; s < 2; ++s)
#pragma unroll
    for (int Mt = 0; Mt < 2; ++Mt)
#pragma unroll
      for (int kx = 0; kx < 3; ++kx) {
        int col = Mt * 32 + kx + lc;
        int q = (2 * s + lh) ^ ((col >> 1) & 3);
        pc[s][Mt][kx] = col * 32 + q * 8;
      }

  float bv[NTILES];
#pragma unroll
  for (int nt = 0; nt < NTILES; ++nt) {
    if (HEAD) {
      bv[nt] = lc < 21 ? bias[lc] : (lc < 24 ? bias2[lc - 21] : 0.f);
    } else {
      bv[nt] = bias[(z * NTILES + nt) * 32 + lc];
    }
  }
  float16 acc[2][NTILES];
#pragma unroll
  for (int Mt = 0; Mt < 2; ++Mt)
#pragma unroll
    for (int nt = 0; nt < NTILES; ++nt)
#pragma unroll
      for (int r = 0; r < 16; ++r) acc[Mt][nt][r] = bv[nt];

  const ushort_t* inbase = in + ((size_t)y0 * PW + x0) * C;
  for (int cc = 0; cc < chunks; ++cc) {
    __syncthreads();
    // stage input chunk: 6 rows x 66 cols x 4 groups of 8ch (16 B units)
    for (int u = tid; u < 1584; u += 256) {
      int r = u / 264;
      int sr = u - r * 264;
      int col = sr >> 2, f = sr & 3;
      int g = f ^ ((col >> 1) & 3);
      const ushort_t* src = inbase + ((size_t)r * PW + col) * C + cc * 32 + g * 8;
      *(uint4*)&s_in[(r * 66 + col) * 32 + f * 8] = *(const uint4*)src;
    }
    // stage weight slice: [pos][s][nt local] x 64 lanes x 16 B
    const int NW = NTILES * 1152;
    for (int u = tid; u < NW; u += 256) {
      int l16 = u & 63, grp = u >> 6;
      int nt = grp % NTILES, ps = grp / NTILES;
      const ushort_t* src =
          w2 + ((size_t)((cc * 18 + ps) * Ntg + z * NTILES + nt) * 64 + l16) * 8;
      *(uint4*)&s_w[(size_t)u * 8] = *(const uint4*)src;
    }
    __syncthreads();
#pragma unroll
    for (int ky = 0; ky < 3; ++ky) {
      int rowoff = (wv + ky) * (66 * 32);
#pragma unroll
      for (int kx = 0; kx < 3; ++kx) {
        const int pos = ky * 3 + kx;
#pragma unroll
        for (int s = 0; s < 2; ++s) {
          short8 Bf[NTILES];
#pragma unroll
          for (int nt = 0; nt < NTILES; ++nt)
            Bf[nt] = *(const short8*)&s_w[((pos * 2 + s) * NTILES + nt) * 512 + lane * 8];
#pragma unroll
          for (int Mt = 0; Mt < 2; ++Mt) {
            short8 Af = *(const short8*)&s_in[rowoff + pc[s][Mt][kx]];
#pragma unroll
            for (int nt = 0; nt < NTILES; ++nt)
              acc[Mt][nt] =
                  __builtin_amdgcn_mfma_f32_32x32x16_bf16(Af, Bf[nt], acc[Mt][nt], 0, 0, 0);
          }
        }
      }
    }
  }

  // epilogue
  int y = y0 + wv;
  if (y >= H) return;
#pragma unroll
  for (int Mt = 0; Mt < 2; ++Mt) {
#pragma unroll
    for (int r = 0; r < 16; ++r) {
      int m = (r & 3) + 8 * (r >> 2) + 4 * lh;
      int x = x0 + Mt * 32 + m;
      if (x < W) {
        size_t sp = (size_t)y * W + x;
        if (HEAD) {
          float v = acc[Mt][0][r];
          if (lc < 21) oba[(size_t)lc * (size_t)(H * W) + sp] = v;
          else if (lc < 24) obb[(size_t)(lc - 21) * (size_t)(H * W) + sp] = v;
        } else {
#pragma unroll
          for (int nt = 0; nt < NTILES; ++nt) {
            int oc = (z * NTILES + nt) * 32 + lc;
            obf[sp * Ntot + oc] = f2bf(acc[Mt][nt][r]);
          }
        }
      }
    }
  }
}

// ------------------------------------------------------------------
// Per-channel stats on bf16 HWC. acc: sum[0..C), sumsq[256..256+C)
// ------------------------------------------------------------------

__global__ __launch_bounds__(256) void stats_bf16(const ushort_t* __restrict__ x,
                                                  float* __restrict__ acc, int HW, int C,
                                                  int cshift) {
  int tid = threadIdx.x;
  int c = tid & (C - 1);
  int pg = tid >> cshift;
  int PPB = 256 >> cshift;
  float s = 0.f, s2 = 0.f;
  for (long p = (long)blockIdx.x * PPB + pg; p < HW; p += (long)gridDim.x * PPB) {
    float v = bf2f(x[(size_t)p * C + c]);
    s += v;
    s2 += v * v;
  }
  __shared__ float r1[256], r2[256];
  r1[tid] = s;
  r2[tid] = s2;
  __syncthreads();
  if (tid < C) {
    for (int o = C; o < 256; o += C) {
      s += r1[tid + o];
      s2 += r2[tid + o];
    }
    atomicAdd(&acc[c], s);
    atomicAdd(&acc[c + 256], s2);
  }
}

__global__ void bn_finalize(const float* __restrict__ acc, const float* __restrict__ g,
                            const float* __restrict__ b, float* __restrict__ ss, int C,
                            float invN) {
  int c = threadIdx.x;
  if (c >= C) return;
  float m = acc[c] * invN;
  float v = acc[c + 256] * invN - m * m;
  v = fmaxf(v, 0.f);
  float inv = rsqrtf(v + BN_EPS);
  float sc = g[c] * inv;
  ss[c] = sc;
  ss[c + 256] = b[c] - m * sc;
}

// BN+relu+2x2pool from bf16 HWC (Wi wide) into padded bf16 HWC (PWo pitch)
__global__ __launch_bounds__(256) void bn_relu_pool_pad(
    const ushort_t* __restrict__ in, const float* __restrict__ ss,
    ushort_t* __restrict__ out, int Wi, int OW, int OH, int C, int cshift, int PWo) {
  int idx = blockIdx.x * 256 + threadIdx.x;
  int total = OH * OW * C;
  if (idx >= total) return;
  int c = idx & (C - 1);
  int p = idx >> cshift;
  int ox = p % OW;
  int oy = p / OW;
  float sc = ss[c], sh = ss[c + 256];
  const ushort_t* ip = in + ((size_t)(2 * oy) * Wi + 2 * ox) * C + c;
  float a = fmaxf(bf2f(ip[0]) * sc + sh, 0.f);
  float b_ = fmaxf(bf2f(ip[C]) * sc + sh, 0.f);
  float d = fmaxf(bf2f(ip[(size_t)Wi * C]) * sc + sh, 0.f);
  float e = fmaxf(bf2f(ip[(size_t)Wi * C + C]) * sc + sh, 0.f);
  float v = fmaxf(fmaxf(a, b_), fmaxf(d, e));
  out[((size_t)(oy + 1) * PWo + (ox + 1)) * C + c] = f2bf(v);
}

// BN+relu (no pool) from bf16 HWC (W=H=166) into padded bf16 HWC
__global__ __launch_bounds__(256) void bn_relu_pad(const ushort_t* __restrict__ in,
                                                   const float* __restrict__ ss,
                                                   ushort_t* __restrict__ out, int Wi,
                                                   int C, int cshift, int PWo) {
  int idx = blockIdx.x * 256 + threadIdx.x;
  int total = Wi * Wi * C;
  if (idx >= total) return;
  int c = idx & (C - 1);
  int p = idx >> cshift;
  int x = p % Wi;
  int y = p / Wi;
  float v = fmaxf(bf2f(in[(size_t)p * C + c]) * ss[c] + ss[c + 256], 0.f);
  out[((size_t)(y + 1) * PWo + (x + 1)) * C + c] = f2bf(v);
}

// ------------------------------------------------------------------

extern "C" void kernel_launch(void* const* d_in, const int* in_sizes, int n_in,
                              void* d_out, int out_size, void* d_ws, size_t ws_size,
                              hipStream_t stream) {
  (void)in_sizes; (void)n_in; (void)out_size; (void)ws_size;
  const float* pillars = (const float*)d_in[0];
  const int* coords = (const int*)d_in[1];
  const float* lin_w = (const float*)d_in[2];
  const float* lin_b = (const float*)d_in[3];
  const float* pfn_g = (const float*)d_in[4];
  const float* pfn_b = (const float*)d_in[5];
  const float* c1_w = (const float*)d_in[6];
  const float* c1_b = (const float*)d_in[7];
  const float* bn1_g = (const float*)d_in[8];
  const float* bn1_b = (const float*)d_in[9];
  const float* c2_w = (const float*)d_in[10];
  const float* c2_b = (const float*)d_in[11];
  const float* bn2_g = (const float*)d_in[12];
  const float* bn2_b = (const float*)d_in[13];
  const float* h1_w = (const float*)d_in[14];
  const float* h1_b = (const float*)d_in[15];
  const float* hbn_g = (const float*)d_in[16];
  const float* hbn_b = (const float*)d_in[17];
  const float* hb_w = (const float*)d_in[18];
  const float* hb_b = (const float*)d_in[19];
  const float* hc_w = (const float*)d_in[20];
  const float* hc_b = (const float*)d_in[21];
  float* out = (float*)d_out;

  // ---- workspace layout (bytes) ----
  char* ws = (char*)d_ws;
  float* pfn_acc = (float*)(ws + 0);            // 512 B
  float* pfn_ss  = (float*)(ws + 512);          // 512 B
  float* bn_acc  = (float*)(ws + 1024);         // 2048 B
  float* ss1     = (float*)(ws + 3072);         // 2048 B
  float* ss2     = (float*)(ws + 5120);         // 2048 B
  float* ss3     = (float*)(ws + 7168);         // 2048 B
  int* winner    = (int*)(ws + 9216);           // 1774224 B
  float* feats   = (float*)(ws + 1783552);      // 5120000 B
  ushort_t* canvas = (ushort_t*)(ws + 6903552);     // 706x670x64 bf16 = 60546560 B
  ushort_t* c1out  = (ushort_t*)(ws + 67450112);    // 666x666x64  = 56775168 B
  ushort_t* c2in   = (ushort_t*)(ws + 124225280);   // 386x338x64  = 16699904 B
  ushort_t* c2out  = (ushort_t*)(ws + 140925184);   // 333x333x128 = 28387584 B
  ushort_t* h1in   = (ushort_t*)(ws + 169312768);   // 194x170x128 = 8442880 B
  ushort_t* h1out  = (ushort_t*)(ws + 177755648);   // 166x166x256 = 14108672 B
  ushort_t* hdin   = (ushort_t*)(ws + 191864320);   // 194x170x256 = 16885760 B
  ushort_t* w2c1   = (ushort_t*)(ws + 208750080);   // 73728 B
  ushort_t* w2c2   = (ushort_t*)(ws + 208823808);   // 147456 B
  ushort_t* w2h1   = (ushort_t*)(ws + 208971264);   // 589824 B
  ushort_t* w2hd   = (ushort_t*)(ws + 209561088);   // 147456 B

  const int HW3 = 166 * 166;

  // ---- zero-init padded buffers & accumulators ----
  hipMemsetAsync(canvas, 0, 60546560, stream);
  hipMemsetAsync(c2in, 0, 16699904, stream);
  hipMemsetAsync(h1in, 0, 8442880, stream);
  hipMemsetAsync(hdin, 0, 16885760, stream);
  hipMemsetAsync(winner, 0xFF, 1774224, stream);
  hipMemsetAsync(pfn_acc, 0, 512, stream);

  // ---- weight prep ----
  prep_w<<<18, 256, 0, stream>>>(c1_w, w2c1, 64, 64, 2, 2);
  prep_w<<<36, 256, 0, stream>>>(c2_w, w2c2, 64, 128, 4, 2);
  prep_w<<<144, 256, 0, stream>>>(h1_w, w2h1, 128, 256, 8, 4);
  prep_w_head<<<36, 256, 0, stream>>>(hb_w, hc_w, w2hd);

  // ---- PFN ----
  pfn_stats<<<625, 256, 0, stream>>>(pillars, lin_w, lin_b, pfn_acc);
  pfn_finalize<<<1, 64, 0, stream>>>(pfn_acc, pfn_g, pfn_b, pfn_ss);
  pfn_feats<<<5000, 256, 0, stream>>>(pillars, lin_w, lin_b, pfn_ss, feats);

  // ---- scatter ----
  scatter_winner<<<(20000 + 255) / 256, 256, 0, stream>>>(coords, winner, 20000);
  scatter_img<<<5000, 256, 0, stream>>>(coords, winner, feats, canvas, 20000, 706);

  // ---- conv1: 666x666, 64->64 ----
  conv_mfma<2, false><<<dim3(11, 167, 1), 256, 0, stream>>>(
      canvas, w2c1, c1_b, nullptr, c1out, nullptr, nullptr, 706, 666, 666, 64, 2);
  hipMemsetAsync(bn_acc, 0, 2048, stream);
  stats_bf16<<<512, 256, 0, stream>>>(c1out, bn_acc, 666 * 666, 64, 6);
  bn_finalize<<<1, 256, 0, stream>>>(bn_acc, bn1_g, bn1_b, ss1, 64, 1.f / 443556.f);
  bn_relu_pool_pad<<<(333 * 333 * 64 + 255) / 256, 256, 0, stream>>>(
      c1out, ss1, c2in, 666, 333, 333, 64, 6, 386);

  // ---- conv2: 333x333, 64->128 ----
  conv_mfma<2, false><<<dim3(6, 84, 2), 256, 0, stream>>>(
      c2in, w2c2, c2_b, nullptr, c2out, nullptr, nullptr, 386, 333, 333, 64, 4);
  hipMemsetAsync(bn_acc, 0, 2048, stream);
  stats_bf16<<<512, 256, 0, stream>>>(c2out, bn_acc, 333 * 333, 128, 7);
  bn_finalize<<<1, 256, 0, stream>>>(bn_acc, bn2_g, bn2_b, ss2, 128, 1.f / 110889.f);
  bn_relu_pool_pad<<<(166 * 166 * 128 + 255) / 256, 256, 0, stream>>>(
      c2out, ss2, h1in, 333, 166, 166, 128, 7, 194);

  // ---- h1: 166x166, 128->256 ----
  conv_mfma<2, false><<<dim3(3, 42, 4), 256, 0, stream>>>(
      h1in, w2h1, h1_b, nullptr, h1out, nullptr, nullptr, 194, 166, 166, 128, 8);
  hipMemsetAsync(bn_acc, 0, 2048, stream);
  stats_bf16<<<512, 256, 0, stream>>>(h1out, bn_acc, HW3, 256, 8);
  bn_finalize<<<1, 256, 0, stream>>>(bn_acc, hbn_g, hbn_b, ss3, 256, 1.f / 27556.f);
  bn_relu_pad<<<(HW3 * 256 + 255) / 256, 256, 0, stream>>>(h1out, ss3, hdin, 166, 256, 8,
                                                           194);

  // ---- heads: 166x166, 256->(21+3), fp32 CHW into d_out ----
  conv_mfma<1, true><<<dim3(3, 42, 1), 256, 0, stream>>>(
      hdin, w2hd, hb_b, hc_b, nullptr, out, out + (size_t)21 * HW3, 194, 166, 166, 256, 1);
}

// Round 3
// 506.683 us; speedup vs baseline: 6.7439x; 1.1319x over previous
//
#include <hip/hip_runtime.h>
#include <hip/hip_bf16.h>
#include <cstdint>
#include <cstddef>

#define BN_EPS 1e-5f

typedef short short8 __attribute__((ext_vector_type(8)));
typedef float float16 __attribute__((ext_vector_type(16)));
typedef unsigned short ushort_t;

__device__ __forceinline__ float bf2f(ushort_t u) {
  return __uint_as_float(((unsigned int)u) << 16);
}
__device__ __forceinline__ ushort_t f2bf(float f) {
  unsigned int u = __float_as_uint(f);
  u += 0x7FFFu + ((u >> 16) & 1u);
  return (ushort_t)(u >> 16);
}

// ------------------------------------------------------------------
// PFN (fp32)
// ------------------------------------------------------------------

__global__ __launch_bounds__(256) void pfn_stats(
    const float* __restrict__ pillars, const float* __restrict__ lin_w,
    const float* __restrict__ lin_b, float* __restrict__ acc) {
  __shared__ float s_p[288];
  __shared__ float red[512];
  int tid = threadIdx.x;
  int c = tid & 63, rs = tid >> 6;
  float w[9];
#pragma unroll
  for (int d = 0; d < 9; ++d) w[d] = lin_w[c * 9 + d];
  float bl = lin_b[c];
  float s = 0.f, s2 = 0.f;
  long base_row = (long)blockIdx.x * 1024;
  for (int ch = 0; ch < 32; ++ch) {
    long crow = base_row + ch * 32;
    __syncthreads();
    for (int i = tid; i < 288; i += 256) s_p[i] = pillars[crow * 9 + i];
    __syncthreads();
#pragma unroll
    for (int k = 0; k < 8; ++k) {
      const float* pr = &s_p[(rs * 8 + k) * 9];
      float y = bl;
#pragma unroll
      for (int d = 0; d < 9; ++d) y += pr[d] * w[d];
      s += y;
      s2 += y * y;
    }
  }
  red[tid] = s;
  red[tid + 256] = s2;
  __syncthreads();
  if (rs == 0) {
    float ts = red[c] + red[c + 64] + red[c + 128] + red[c + 192];
    float t2 = red[256 + c] + red[256 + c + 64] + red[256 + c + 128] + red[256 + c + 192];
    atomicAdd(&acc[c], ts);
    atomicAdd(&acc[c + 64], t2);
  }
}

__global__ void pfn_finalize(const float* __restrict__ acc, const float* __restrict__ g,
                             const float* __restrict__ b, float* __restrict__ ss) {
  int c = threadIdx.x;  // 64 threads
  const float invN = 1.f / 640000.f;
  float m = acc[c] * invN;
  float v = acc[c + 64] * invN - m * m;
  v = fmaxf(v, 0.f);
  float inv = rsqrtf(v + BN_EPS);
  float sc = g[c] * inv;
  ss[c] = sc;
  ss[c + 64] = b[c] - m * sc;
}

__global__ __launch_bounds__(256) void pfn_feats(
    const float* __restrict__ pillars, const float* __restrict__ lin_w,
    const float* __restrict__ lin_b, const float* __restrict__ ss,
    float* __restrict__ feats) {
  __shared__ float s_p[1152];
  int tid = threadIdx.x;
  int c = tid & 63, pe = tid >> 6;
  long pb = (long)blockIdx.x * 4;
  for (int i = tid; i < 1152; i += 256) s_p[i] = pillars[pb * 288 + i];
  float w[9];
#pragma unroll
  for (int d = 0; d < 9; ++d) w[d] = lin_w[c * 9 + d];
  float bl = lin_b[c];
  float sc = ss[c], sh = ss[c + 64];
  __syncthreads();
  const float* pp = &s_p[pe * 288];
  float m = -1e30f;
#pragma unroll 4
  for (int n = 0; n < 32; ++n) {
    float y = bl;
#pragma unroll
    for (int d = 0; d < 9; ++d) y += pp[n * 9 + d] * w[d];
    float v = fmaxf(y * sc + sh, 0.f);
    m = fmaxf(m, v);
  }
  feats[(pb + pe) * 64 + c] = m;
}

// ------------------------------------------------------------------
// Scatter into padded bf16 HWC canvas (numpy last-write-wins)
// ------------------------------------------------------------------

__global__ void scatter_winner(const int* __restrict__ coords, int* __restrict__ winner,
                               int P) {
  int p = blockIdx.x * 256 + threadIdx.x;
  if (p >= P) return;
  int y = coords[p * 3 + 1], x = coords[p * 3 + 2];
  if (y >= 0 && y < 666 && x >= 0 && x < 666) atomicMax(&winner[y * 666 + x], p);
}

__global__ void scatter_img(const int* __restrict__ coords, const int* __restrict__ winner,
                            const float* __restrict__ feats, ushort_t* __restrict__ img,
                            int P, int PW) {
  int idx = blockIdx.x * 256 + threadIdx.x;
  int p = idx >> 6, c = idx & 63;
  if (p >= P) return;
  int y = coords[p * 3 + 1], x = coords[p * 3 + 2];
  if (y >= 0 && y < 666 && x >= 0 && x < 666) {
    if (winner[y * 666 + x] == p)
      img[((size_t)(y + 1) * PW + (x + 1)) * 64 + c] = f2bf(feats[p * 64 + c]);
  }
}

// ------------------------------------------------------------------
// Weight prep: OIHW fp32 -> fragment-ordered bf16, K-chunk = 16.
// layout: [cc][pos][ntg][lane 64][8]  (lane l: n=ntg*32+(l&31), k=(l>>5)*8+j, c=cc*16+k)
// ------------------------------------------------------------------

__global__ void prep_w(const float* __restrict__ w, ushort_t* __restrict__ w2, int C,
                       int N, int Ntg, int chunks) {
  int u = blockIdx.x * 256 + threadIdx.x;
  int total = chunks * 9 * Ntg * 64;
  if (u >= total) return;
  int l = u & 63;
  int g = u >> 6;
  int ntg = g % Ntg;
  int g2 = g / Ntg;
  int pos = g2 % 9;
  int cc = g2 / 9;
  int n = ntg * 32 + (l & 31);
  int c0 = cc * 16 + (l >> 5) * 8;
  ushort_t o8[8];
#pragma unroll
  for (int j = 0; j < 8; ++j) {
    int c = c0 + j;
    float v = (n < N && c < C) ? w[((size_t)n * C + c) * 9 + pos] : 0.f;
    o8[j] = f2bf(v);
  }
  *(uint4*)&w2[(size_t)u * 8] = *(const uint4*)o8;
}

// merged heads: n<21 -> hb_w, 21..23 -> hc_w, >=24 -> 0.  C=256, Ntg=1, chunks=16
__global__ void prep_w_head(const float* __restrict__ hb, const float* __restrict__ hc,
                            ushort_t* __restrict__ w2) {
  int u = blockIdx.x * 256 + threadIdx.x;
  int total = 16 * 9 * 64;
  if (u >= total) return;
  int l = u & 63;
  int g = u >> 6;
  int pos = g % 9;
  int cc = g / 9;
  int n = l & 31;
  int c0 = cc * 16 + (l >> 5) * 8;
  ushort_t o8[8];
#pragma unroll
  for (int j = 0; j < 8; ++j) {
    int c = c0 + j;
    float v = 0.f;
    if (n < 21) v = hb[((size_t)n * 256 + c) * 9 + pos];
    else if (n < 24) v = hc[((size_t)(n - 21) * 256 + c) * 9 + pos];
    o8[j] = f2bf(v);
  }
  *(uint4*)&w2[(size_t)u * 8] = *(const uint4*)o8;
}

// ------------------------------------------------------------------
// Implicit-GEMM 3x3 conv via v_mfma_f32_32x32x16_bf16, K-chunk = 16.
// Block = 4 waves. Tile 64 px wide x 4 rows, NT*32 oc per block.
// LDS = 12672 (input) + 9216*NT (weights) -> 31104 B for NT=2 -> 5 blocks/CU.
// HEAD: blockIdx.z is a K-split (cc0 = z*C16); fp32 atomicAdd epilogue.
// STATS: fused per-channel sum/sumsq block-reduce + atomicAdd.
// ------------------------------------------------------------------

template <int NT, bool HEAD, bool STATS>
__global__ __launch_bounds__(256, 5) void conv_mfma(
    const ushort_t* __restrict__ in, const ushort_t* __restrict__ w2,
    const float* __restrict__ bias, const float* __restrict__ bias2,
    ushort_t* __restrict__ obf, float* __restrict__ oba, float* __restrict__ obb,
    float* __restrict__ statacc, int PW, int W, int H, int C, int C16, int Ntg) {
  __shared__ ushort_t s_in[6 * 66 * 16];   // 12672 B
  __shared__ ushort_t s_w[9 * NT * 512];   // 9216*NT B
  const int tid = threadIdx.x;
  const int lane = tid & 63, wv = tid >> 6;
  const int lc = lane & 31, lh = lane >> 5;
  const int x0 = blockIdx.x * 64, y0 = blockIdx.y * 4;
  const int z = blockIdx.z;
  const int cc0 = HEAD ? z * C16 : 0;
  const int z_oc = HEAD ? 0 : z;

  // per-lane A offsets (element units within a staged row)
  int pa[2][3];
#pragma unroll
  for (int Mt = 0; Mt < 2; ++Mt)
#pragma unroll
    for (int kx = 0; kx < 3; ++kx) {
      int col = Mt * 32 + kx + lc;
      int slot = lh ^ ((col >> 2) & 1);
      pa[Mt][kx] = col * 16 + slot * 8;
    }

  float bv[NT];
#pragma unroll
  for (int nt = 0; nt < NT; ++nt) {
    if (HEAD) {
      bv[nt] = (z == 0) ? (lc < 21 ? bias[lc] : (lc < 24 ? bias2[lc - 21] : 0.f)) : 0.f;
    } else {
      bv[nt] = bias[(z * NT + nt) * 32 + lc];
    }
  }
  float16 acc[2][NT];
#pragma unroll
  for (int Mt = 0; Mt < 2; ++Mt)
#pragma unroll
    for (int nt = 0; nt < NT; ++nt)
#pragma unroll
      for (int r = 0; r < 16; ++r) acc[Mt][nt][r] = bv[nt];

  const ushort_t* inbase = in + ((size_t)y0 * PW + x0) * C;
  for (int cc = 0; cc < C16; ++cc) {
    int ccg = cc0 + cc;
    __syncthreads();
    // stage input: 792 16B units, linear LDS write, swizzled source half
    for (int u = tid; u < 792; u += 256) {
      int r = u / 132;
      int rem = u - r * 132;
      int col = rem >> 1, s = rem & 1;
      int h = s ^ ((col >> 2) & 1);
      const ushort_t* src = inbase + ((size_t)r * PW + col) * C + ccg * 16 + h * 8;
      *(uint4*)&s_in[(size_t)u * 8] = *(const uint4*)src;
    }
    // stage weights: 9*NT*64 16B units
    const int NWU = 9 * NT * 64;
    for (int u = tid; u < NWU; u += 256) {
      int l16 = u & 63, grp = u >> 6;
      int nt = grp % NT, pos = grp / NT;
      const ushort_t* src =
          w2 + ((size_t)(ccg * 9 + pos) * Ntg + (z_oc * NT + nt)) * 512 + (size_t)l16 * 8;
      *(uint4*)&s_w[(size_t)u * 8] = *(const uint4*)src;
    }
    __syncthreads();
#pragma unroll
    for (int ky = 0; ky < 3; ++ky) {
      const int rowoff = (wv + ky) * (66 * 16);
#pragma unroll
      for (int kx = 0; kx < 3; ++kx) {
        const int pos = ky * 3 + kx;
        short8 Bf[NT];
#pragma unroll
        for (int nt = 0; nt < NT; ++nt)
          Bf[nt] = *(const short8*)&s_w[(pos * NT + nt) * 512 + lane * 8];
#pragma unroll
        for (int Mt = 0; Mt < 2; ++Mt) {
          short8 Af = *(const short8*)&s_in[rowoff + pa[Mt][kx]];
#pragma unroll
          for (int nt = 0; nt < NT; ++nt)
            acc[Mt][nt] =
                __builtin_amdgcn_mfma_f32_32x32x16_bf16(Af, Bf[nt], acc[Mt][nt], 0, 0, 0);
        }
      }
    }
  }

  // ---- epilogue ----
  const int y = y0 + wv;
  const bool yok = (y < H);
  if (HEAD) {
    if (yok) {
#pragma unroll
      for (int Mt = 0; Mt < 2; ++Mt)
#pragma unroll
        for (int r = 0; r < 16; ++r) {
          int m = (r & 3) + 8 * (r >> 2) + 4 * lh;
          int x = x0 + Mt * 32 + m;
          if (x < W) {
            size_t sp = (size_t)y * W + x;
            float v = acc[Mt][0][r];
            if (lc < 21) atomicAdd(&oba[(size_t)lc * (size_t)(H * W) + sp], v);
            else if (lc < 24) atomicAdd(&obb[(size_t)(lc - 21) * (size_t)(H * W) + sp], v);
          }
        }
    }
    return;
  }

  const int Ntot = Ntg * 32;
  if (yok) {
#pragma unroll
    for (int Mt = 0; Mt < 2; ++Mt)
#pragma unroll
      for (int r = 0; r < 16; ++r) {
        int m = (r & 3) + 8 * (r >> 2) + 4 * lh;
        int x = x0 + Mt * 32 + m;
        if (x < W) {
          size_t sp = (size_t)y * W + x;
#pragma unroll
          for (int nt = 0; nt < NT; ++nt) {
            int oc = (z * NT + nt) * 32 + lc;
            obf[sp * Ntot + oc] = f2bf(acc[Mt][nt][r]);
          }
        }
      }
  }

  if (STATS) {
    float s1[NT], s2[NT];
#pragma unroll
    for (int nt = 0; nt < NT; ++nt) { s1[nt] = 0.f; s2[nt] = 0.f; }
    if (yok) {
#pragma unroll
      for (int Mt = 0; Mt < 2; ++Mt)
#pragma unroll
        for (int r = 0; r < 16; ++r) {
          int m = (r & 3) + 8 * (r >> 2) + 4 * lh;
          int x = x0 + Mt * 32 + m;
          if (x < W) {
#pragma unroll
            for (int nt = 0; nt < NT; ++nt) {
              float v = acc[Mt][nt][r];
              s1[nt] += v;
              s2[nt] += v * v;
            }
          }
        }
    }
#pragma unroll
    for (int nt = 0; nt < NT; ++nt) {
      s1[nt] += __shfl_xor(s1[nt], 32);
      s2[nt] += __shfl_xor(s2[nt], 32);
    }
    __syncthreads();  // all MFMA LDS reads done; reuse s_in as fp32 scratch
    float* red = (float*)s_in;
    if (lh == 0) {
#pragma unroll
      for (int nt = 0; nt < NT; ++nt) {
        red[(wv * NT + nt) * 32 + lc] = s1[nt];
        red[4 * NT * 32 + (wv * NT + nt) * 32 + lc] = s2[nt];
      }
    }
    __syncthreads();
    if (wv == 0 && lh == 0) {
#pragma unroll
      for (int nt = 0; nt < NT; ++nt) {
        float a = 0.f, b = 0.f;
#pragma unroll
        for (int w4 = 0; w4 < 4; ++w4) {
          a += red[(w4 * NT + nt) * 32 + lc];
          b += red[4 * NT * 32 + (w4 * NT + nt) * 32 + lc];
        }
        int ch = (z * NT + nt) * 32 + lc;
        atomicAdd(&statacc[ch], a);
        atomicAdd(&statacc[ch + 256], b);
      }
    }
  }
}

// ------------------------------------------------------------------
// BN finalize + elementwise
// ------------------------------------------------------------------

__global__ void bn_finalize(const float* __restrict__ acc, const float* __restrict__ g,
                            const float* __restrict__ b, float* __restrict__ ss, int C,
                            float invN) {
  int c = threadIdx.x;
  if (c >= C) return;
  float m = acc[c] * invN;
  float v = acc[c + 256] * invN - m * m;
  v = fmaxf(v, 0.f);
  float inv = rsqrtf(v + BN_EPS);
  float sc = g[c] * inv;
  ss[c] = sc;
  ss[c + 256] = b[c] - m * sc;
}

// BN+relu+2x2pool from bf16 HWC (Wi wide) into padded bf16 HWC (PWo pitch)
__global__ __launch_bounds__(256) void bn_relu_pool_pad(
    const ushort_t* __restrict__ in, const float* __restrict__ ss,
    ushort_t* __restrict__ out, int Wi, int OW, int OH, int C, int cshift, int PWo) {
  int idx = blockIdx.x * 256 + threadIdx.x;
  int total = OH * OW * C;
  if (idx >= total) return;
  int c = idx & (C - 1);
  int p = idx >> cshift;
  int ox = p % OW;
  int oy = p / OW;
  float sc = ss[c], sh = ss[c + 256];
  const ushort_t* ip = in + ((size_t)(2 * oy) * Wi + 2 * ox) * C + c;
  float a = fmaxf(bf2f(ip[0]) * sc + sh, 0.f);
  float b_ = fmaxf(bf2f(ip[C]) * sc + sh, 0.f);
  float d = fmaxf(bf2f(ip[(size_t)Wi * C]) * sc + sh, 0.f);
  float e = fmaxf(bf2f(ip[(size_t)Wi * C + C]) * sc + sh, 0.f);
  float v = fmaxf(fmaxf(a, b_), fmaxf(d, e));
  out[((size_t)(oy + 1) * PWo + (ox + 1)) * C + c] = f2bf(v);
}

// BN+relu (no pool) from bf16 HWC into padded bf16 HWC
__global__ __launch_bounds__(256) void bn_relu_pad(const ushort_t* __restrict__ in,
                                                   const float* __restrict__ ss,
                                                   ushort_t* __restrict__ out, int Wi,
                                                   int C, int cshift, int PWo) {
  int idx = blockIdx.x * 256 + threadIdx.x;
  int total = Wi * Wi * C;
  if (idx >= total) return;
  int c = idx & (C - 1);
  int p = idx >> cshift;
  int x = p % Wi;
  int y = p / Wi;
  float v = fmaxf(bf2f(in[(size_t)p * C + c]) * ss[c] + ss[c + 256], 0.f);
  out[((size_t)(y + 1) * PWo + (x + 1)) * C + c] = f2bf(v);
}

// ------------------------------------------------------------------

extern "C" void kernel_launch(void* const* d_in, const int* in_sizes, int n_in,
                              void* d_out, int out_size, void* d_ws, size_t ws_size,
                              hipStream_t stream) {
  (void)in_sizes; (void)n_in; (void)out_size; (void)ws_size;
  const float* pillars = (const float*)d_in[0];
  const int* coords = (const int*)d_in[1];
  const float* lin_w = (const float*)d_in[2];
  const float* lin_b = (const float*)d_in[3];
  const float* pfn_g = (const float*)d_in[4];
  const float* pfn_b = (const float*)d_in[5];
  const float* c1_w = (const float*)d_in[6];
  const float* c1_b = (const float*)d_in[7];
  const float* bn1_g = (const float*)d_in[8];
  const float* bn1_b = (const float*)d_in[9];
  const float* c2_w = (const float*)d_in[10];
  const float* c2_b = (const float*)d_in[11];
  const float* bn2_g = (const float*)d_in[12];
  const float* bn2_b = (const float*)d_in[13];
  const float* h1_w = (const float*)d_in[14];
  const float* h1_b = (const float*)d_in[15];
  const float* hbn_g = (const float*)d_in[16];
  const float* hbn_b = (const float*)d_in[17];
  const float* hb_w = (const float*)d_in[18];
  const float* hb_b = (const float*)d_in[19];
  const float* hc_w = (const float*)d_in[20];
  const float* hc_b = (const float*)d_in[21];
  float* out = (float*)d_out;

  // ---- workspace layout (bytes) ----
  char* ws = (char*)d_ws;
  float* pfn_acc = (float*)(ws + 0);         // 512 B
  float* pfn_ss  = (float*)(ws + 512);       // 512 B
  float* bn_acc1 = (float*)(ws + 1024);      // 2048 B
  float* bn_acc2 = (float*)(ws + 3072);      // 2048 B
  float* bn_acc3 = (float*)(ws + 5120);      // 2048 B
  float* ss1     = (float*)(ws + 7168);      // 2048 B
  float* ss2     = (float*)(ws + 9216);      // 2048 B
  float* ss3     = (float*)(ws + 11264);     // 2048 B
  int* winner    = (int*)(ws + 13312);       // 1774224 B
  float* feats   = (float*)(ws + 1787648);   // 5120000 B
  ushort_t* canvas = (ushort_t*)(ws + 6907648);     // 706x670x64   = 60546560 B
  ushort_t* c1out  = (ushort_t*)(ws + 67454208);    // 666x666x64   = 56775168 B
  ushort_t* c2in   = (ushort_t*)(ws + 124229376);   // 386x338x64   = 16699904 B
  ushort_t* c2out  = (ushort_t*)(ws + 140929280);   // 333x333x128  = 28387584 B
  ushort_t* h1in   = (ushort_t*)(ws + 169316864);   // 194x170x128  = 8442880 B
  ushort_t* h1out  = (ushort_t*)(ws + 177759744);   // 166x166x256  = 14108672 B
  ushort_t* hdin   = (ushort_t*)(ws + 191868416);   // 194x170x256  = 16885760 B
  ushort_t* w2c1   = (ushort_t*)(ws + 208754176);   // 73728 B
  ushort_t* w2c2   = (ushort_t*)(ws + 208827904);   // 147456 B
  ushort_t* w2h1   = (ushort_t*)(ws + 208975360);   // 589824 B
  ushort_t* w2hd   = (ushort_t*)(ws + 209565184);   // 147456 B

  const int HW3 = 166 * 166;

  // ---- upfront zero-init ----
  hipMemsetAsync(ws, 0, 7168, stream);  // pfn_acc/pfn_ss/bn_acc1-3
  hipMemsetAsync(winner, 0xFF, 1774224, stream);
  hipMemsetAsync(canvas, 0, 60546560, stream);
  hipMemsetAsync(c2in, 0, 16699904, stream);
  hipMemsetAsync(h1in, 0, 8442880, stream);
  hipMemsetAsync(hdin, 0, 16885760, stream);
  hipMemsetAsync(out, 0, (size_t)24 * HW3 * 4, stream);  // head accumulates via atomics

  // ---- weight prep (Kc=16 layout) ----
  prep_w<<<18, 256, 0, stream>>>(c1_w, w2c1, 64, 64, 2, 4);
  prep_w<<<36, 256, 0, stream>>>(c2_w, w2c2, 64, 128, 4, 4);
  prep_w<<<144, 256, 0, stream>>>(h1_w, w2h1, 128, 256, 8, 8);
  prep_w_head<<<36, 256, 0, stream>>>(hb_w, hc_w, w2hd);

  // ---- PFN ----
  pfn_stats<<<625, 256, 0, stream>>>(pillars, lin_w, lin_b, pfn_acc);
  pfn_finalize<<<1, 64, 0, stream>>>(pfn_acc, pfn_g, pfn_b, pfn_ss);
  pfn_feats<<<5000, 256, 0, stream>>>(pillars, lin_w, lin_b, pfn_ss, feats);

  // ---- scatter ----
  scatter_winner<<<(20000 + 255) / 256, 256, 0, stream>>>(coords, winner, 20000);
  scatter_img<<<5000, 256, 0, stream>>>(coords, winner, feats, canvas, 20000, 706);

  // ---- conv1: 666x666, 64->64 (stats fused) ----
  conv_mfma<2, false, true><<<dim3(11, 167, 1), 256, 0, stream>>>(
      canvas, w2c1, c1_b, nullptr, c1out, nullptr, nullptr, bn_acc1, 706, 666, 666, 64,
      4, 2);
  bn_finalize<<<1, 256, 0, stream>>>(bn_acc1, bn1_g, bn1_b, ss1, 64, 1.f / 443556.f);
  bn_relu_pool_pad<<<(333 * 333 * 64 + 255) / 256, 256, 0, stream>>>(
      c1out, ss1, c2in, 666, 333, 333, 64, 6, 386);

  // ---- conv2: 333x333, 64->128 (stats fused) ----
  conv_mfma<2, false, true><<<dim3(6, 84, 2), 256, 0, stream>>>(
      c2in, w2c2, c2_b, nullptr, c2out, nullptr, nullptr, bn_acc2, 386, 333, 333, 64, 4,
      4);
  bn_finalize<<<1, 256, 0, stream>>>(bn_acc2, bn2_g, bn2_b, ss2, 128, 1.f / 110889.f);
  bn_relu_pool_pad<<<(166 * 166 * 128 + 255) / 256, 256, 0, stream>>>(
      c2out, ss2, h1in, 333, 166, 166, 128, 7, 194);

  // ---- h1: 166x166, 128->256 (stats fused) ----
  conv_mfma<2, false, true><<<dim3(3, 42, 4), 256, 0, stream>>>(
      h1in, w2h1, h1_b, nullptr, h1out, nullptr, nullptr, bn_acc3, 194, 166, 166, 128, 8,
      8);
  bn_finalize<<<1, 256, 0, stream>>>(bn_acc3, hbn_g, hbn_b, ss3, 256, 1.f / 27556.f);
  bn_relu_pad<<<(HW3 * 256 + 255) / 256, 256, 0, stream>>>(h1out, ss3, hdin, 166, 256, 8,
                                                           194);

  // ---- heads: 166x166, 256->(21+3), K-split z=2, fp32 atomics into d_out ----
  conv_mfma<1, true, false><<<dim3(3, 42, 2), 256, 0, stream>>>(
      hdin, w2hd, hb_b, hc_b, nullptr, out, out + (size_t)21 * HW3, nullptr, 194, 166,
      166, 256, 8, 1);
}